// Round 1
// baseline (342.258 us; speedup 1.0000x reference)
//
#include <hip/hip_runtime.h>

// VIF SSIM loss: block-mean statistics over non-overlapping 11x11 blocks of
// three f32 images (vis, ir, fusion), per-block SSIM-style score, global mean.
// Memory-bound: 380.6 MB read / ~60 us floor at 6.3 TB/s.

namespace {
constexpr int K      = 11;
constexpr int W      = 1408;
constexpr int H      = 1408;
constexpr int B      = 16;
constexpr int BPR    = W / K;   // 128 blocks per row
constexpr int BROWS  = H / K;   // 128 block rows
constexpr int CHUNKS = W / 4;   // 352 float4 chunks per image row
constexpr float C_C  = 0.0009f;
constexpr float INV_KK = 1.0f / (float)(K * K);
}

__device__ __forceinline__ void acc4(float4& a, const float4 v) {
    a.x += v.x; a.y += v.y; a.z += v.z; a.w += v.w;
}
__device__ __forceinline__ void fma4(float4& a, const float4 u, const float4 v) {
    a.x += u.x * v.x; a.y += u.y * v.y; a.z += u.z * v.z; a.w += u.w * v.w;
}

__global__ __launch_bounds__(256) void vif_pass1(
    const float* __restrict__ vis,
    const float* __restrict__ ir,
    const float* __restrict__ fus,
    double* __restrict__ accum)
{
    // Per-column partial sums over the 11 rows of this block-row strip.
    // 8 quantities x 1408 columns x 4 B = 45056 B LDS -> 3 blocks/CU.
    __shared__ float s[8][W];
    __shared__ float wsum[4];

    const int t  = threadIdx.x;
    const int b  = blockIdx.x >> 7;    // batch (grid = B * BROWS, BROWS=128)
    const int br = blockIdx.x & 127;   // block row
    const size_t base = (size_t)b * ((size_t)H * W) + (size_t)br * K * W;

    // ---- Phase 1: stream 11 rows x 3 images, coalesced float4 ----
    for (int c = t; c < CHUNKS; c += 256) {
        float4 sv  = make_float4(0.f, 0.f, 0.f, 0.f);
        float4 sv2 = make_float4(0.f, 0.f, 0.f, 0.f);
        float4 si  = make_float4(0.f, 0.f, 0.f, 0.f);
        float4 si2 = make_float4(0.f, 0.f, 0.f, 0.f);
        float4 sf  = make_float4(0.f, 0.f, 0.f, 0.f);
        float4 sf2 = make_float4(0.f, 0.f, 0.f, 0.f);
        float4 svf = make_float4(0.f, 0.f, 0.f, 0.f);
        float4 sif = make_float4(0.f, 0.f, 0.f, 0.f);
        const size_t off = base + (size_t)c * 4;
#pragma unroll
        for (int r = 0; r < K; ++r) {
            const size_t o = off + (size_t)r * W;
            const float4 v = *(const float4*)(vis + o);
            const float4 i = *(const float4*)(ir  + o);
            const float4 f = *(const float4*)(fus + o);
            acc4(sv, v);
            fma4(sv2, v, v);
            acc4(si, i);
            fma4(si2, i, i);
            acc4(sf, f);
            fma4(sf2, f, f);
            fma4(svf, v, f);
            fma4(sif, i, f);
        }
        const int col = c * 4;
        *(float4*)&s[0][col] = sv;
        *(float4*)&s[1][col] = sv2;
        *(float4*)&s[2][col] = si;
        *(float4*)&s[3][col] = si2;
        *(float4*)&s[4][col] = sf;
        *(float4*)&s[5][col] = sf2;
        *(float4*)&s[6][col] = svf;
        *(float4*)&s[7][col] = sif;
    }
    __syncthreads();

    // ---- Phase 2: fold 11 columns per block, compute score ----
    float score = 0.0f;
    if (t < BPR) {
        float a0 = 0.f, a1 = 0.f, a2 = 0.f, a3 = 0.f;
        float a4 = 0.f, a5 = 0.f, a6 = 0.f, a7 = 0.f;
        const int c0 = t * K;   // stride 11: coprime with 32 banks -> 2-way only (free)
#pragma unroll
        for (int k = 0; k < K; ++k) {
            a0 += s[0][c0 + k];
            a1 += s[1][c0 + k];
            a2 += s[2][c0 + k];
            a3 += s[3][c0 + k];
            a4 += s[4][c0 + k];
            a5 += s[5][c0 + k];
            a6 += s[6][c0 + k];
            a7 += s[7][c0 + k];
        }
        const float vm  = a0 * INV_KK;
        const float vs2 = a1 * INV_KK;
        const float im  = a2 * INV_KK;
        const float is2 = a3 * INV_KK;
        const float fm  = a4 * INV_KK;
        const float fs2 = a5 * INV_KK;
        const float vfm = a6 * INV_KK;
        const float ifm = a7 * INV_KK;

        const float vv = fabsf(vs2 - vm * vm);
        const float iv = fabsf(is2 - im * im);
        const float fv = fabsf(fs2 - fm * fm);
        const float vf_cov = vfm - vm * fm;
        const float if_cov = ifm - im * fm;

        const float l_vf = (2.f * vm * fm + C_C) / (vm * vm + fm * fm + C_C);
        const float l_if = (2.f * im * fm + C_C) / (im * im + fm * fm + C_C);
        const float s_vf = (vf_cov + C_C) / (vv + fv + C_C);
        const float s_if = (if_cov + C_C) / (iv + fv + C_C);

        score = (vm > im) ? (l_vf * s_vf) : (l_if * s_if);
    }

    // ---- Reduce 128 scores -> one double atomic per workgroup ----
#pragma unroll
    for (int o = 32; o > 0; o >>= 1) score += __shfl_down(score, o, 64);
    if ((t & 63) == 0) wsum[t >> 6] = score;
    __syncthreads();
    if (t == 0) {
        const double tot = (double)(wsum[0] + wsum[1] + wsum[2] + wsum[3]);
        atomicAdd(accum, tot);
    }
}

__global__ void vif_finalize(const double* __restrict__ accum,
                             float* __restrict__ out)
{
    if (threadIdx.x == 0 && blockIdx.x == 0) {
        out[0] = 1.0f - (float)(accum[0] / (double)(B * BROWS * BPR));
    }
}

extern "C" void kernel_launch(void* const* d_in, const int* in_sizes, int n_in,
                              void* d_out, int out_size, void* d_ws, size_t ws_size,
                              hipStream_t stream) {
    const float* vis = (const float*)d_in[0];
    const float* ir  = (const float*)d_in[1];
    const float* fus = (const float*)d_in[2];
    float* out = (float*)d_out;
    double* accum = (double*)d_ws;

    // d_ws is re-poisoned to 0xAA before every timed launch; zero it.
    hipMemsetAsync(accum, 0, sizeof(double), stream);
    vif_pass1<<<dim3(B * BROWS), dim3(256), 0, stream>>>(vis, ir, fus, accum);
    vif_finalize<<<dim3(1), dim3(64), 0, stream>>>(accum, out);
}